// Round 1
// baseline (192.417 us; speedup 1.0000x reference)
//
#include <hip/hip_runtime.h>

#define EPB 32          // envs per block (8 per wave)
#define BLOCK 256       // 4 independent waves; env = 8 lanes, wave-internal
#define HS 292          // H LDS stride (288 + 4)
#define GS 148          // G/Ginv LDS stride (144 + 4)
#define SS 28           // b / aux stride (24 + 4)

#define WFENCE() __builtin_amdgcn_wave_barrier()   // compiler fence, 0 instr

#define DPP_XOR1 0xB1   // quad_perm [1,0,3,2]  : lane ^= 1
#define DPP_XOR2 0x4E   // quad_perm [2,3,0,1]  : lane ^= 2
#define DPP_HMIR 0x141  // row_half_mirror      : lane ^= 7 (within 8)

// gather slot-group g (0..7) holds the s-triple of lane (t ^ GMAP[g]):
// slots built as [own, xor1, xor2(own,xor1), hmir(first 12)]
constexpr int GMAP[8] = {0, 1, 2, 3, 7, 6, 5, 4};

// acc += dot(f4, s4)
#define FMA4(acc, f, s)                                         \
  acc = fmaf((f).x, (s).x,                                      \
        fmaf((f).y, (s).y,                                      \
        fmaf((f).z, (s).z,                                      \
        fmaf((f).w, (s).w, (acc)))))

// acc4 += s * v4
#define VFMA(acc, s, v)                                         \
  { (acc).x = fmaf((s), (v).x, (acc).x);                        \
    (acc).y = fmaf((s), (v).y, (acc).y);                        \
    (acc).z = fmaf((s), (v).z, (acc).z);                        \
    (acc).w = fmaf((s), (v).w, (acc).w); }

#define ADD4(A, B) { (A).x += (B).x; (A).y += (B).y; (A).z += (B).z; (A).w += (B).w; }

template<int CTRL>
__device__ __forceinline__ float dppv(float v) {
  return __int_as_float(__builtin_amdgcn_update_dpp(
      0, __float_as_int(v), CTRL, 0xF, 0xF, true));
}

template<int K>
__device__ __forceinline__ float getel(const float4& a, const float4& b, const float4& c) {
  if constexpr (K == 0) return a.x; else if constexpr (K == 1) return a.y;
  else if constexpr (K == 2) return a.z; else if constexpr (K == 3) return a.w;
  else if constexpr (K == 4) return b.x; else if constexpr (K == 5) return b.y;
  else if constexpr (K == 6) return b.z; else if constexpr (K == 7) return b.w;
  else if constexpr (K == 8) return c.x; else if constexpr (K == 9) return c.y;
  else if constexpr (K == 10) return c.z; else return c.w;
}
template<int K>
__device__ __forceinline__ void setel(float4& a, float4& b, float4& c, float v) {
  if constexpr (K == 0) a.x = v; else if constexpr (K == 1) a.y = v;
  else if constexpr (K == 2) a.z = v; else if constexpr (K == 3) a.w = v;
  else if constexpr (K == 4) b.x = v; else if constexpr (K == 5) b.y = v;
  else if constexpr (K == 6) b.z = v; else if constexpr (K == 7) b.w = v;
  else if constexpr (K == 8) c.x = v; else if constexpr (K == 9) c.y = v;
  else if constexpr (K == 10) c.z = v; else c.w = v;
}

// write scalar into slot S (0..23) of a float4[6] row (all-constant indices)
template<int S>
__device__ __forceinline__ void putS(float4* m, float v) {
  constexpr int Q = S >> 2, R = S & 3;
  if constexpr (R == 0) m[Q].x = v;
  else if constexpr (R == 1) m[Q].y = v;
  else if constexpr (R == 2) m[Q].z = v;
  else m[Q].w = v;
}

__device__ __forceinline__ float dot12(float4 a0, float4 a1, float4 a2,
                                       const float* p) {
  const float4* p4 = (const float4*)p;
  float4 b0 = p4[0], b1 = p4[1], b2 = p4[2];
  float acc = 0.f;
  FMA4(acc, a0, b0); FMA4(acc, a1, b1); FMA4(acc, a2, b2);
  return acc;
}

// ---- register-resident Gauss-Jordan (SPD, no pivoting) --------------------
// Thread keeps rows t and t+8 (i1) in registers; only the pivot row goes
// through LDS (3 stores by owner, 3 broadcast loads by everyone).
template<int K>
__device__ __forceinline__ void pivot_pub(float4& a, float4& b, float4& c, float* piv) {
  float ip = 1.0f / getel<K>(a, b, c);
  setel<K>(a, b, c, 1.0f);
  a.x *= ip; a.y *= ip; a.z *= ip; a.w *= ip;
  b.x *= ip; b.y *= ip; b.z *= ip; b.w *= ip;
  c.x *= ip; c.y *= ip; c.z *= ip; c.w *= ip;
  float4* pv = (float4*)piv;
  pv[0] = a; pv[1] = b; pv[2] = c;
}

#define ELIM(f, A, B, C)                                              \
  { (A).x = fmaf(-(f), p0.x, (A).x); (A).y = fmaf(-(f), p0.y, (A).y); \
    (A).z = fmaf(-(f), p0.z, (A).z); (A).w = fmaf(-(f), p0.w, (A).w); \
    (B).x = fmaf(-(f), p1.x, (B).x); (B).y = fmaf(-(f), p1.y, (B).y); \
    (B).z = fmaf(-(f), p1.z, (B).z); (B).w = fmaf(-(f), p1.w, (B).w); \
    (C).x = fmaf(-(f), p2.x, (C).x); (C).y = fmaf(-(f), p2.y, (C).y); \
    (C).z = fmaf(-(f), p2.z, (C).z); (C).w = fmaf(-(f), p2.w, (C).w); }

template<int K>
__device__ __forceinline__ void rgj_step(float4& a0, float4& b0, float4& c0,
                                         float4& a1, float4& b1, float4& c1,
                                         float* piv, int t) {
  if constexpr (K < 8) {
    if (t == K) pivot_pub<K>(a0, b0, c0, piv);
  } else {
    if (t == K - 8) pivot_pub<K>(a1, b1, c1, piv);
  }
  WFENCE();
  const float4* pv = (const float4*)piv;
  float4 p0 = pv[0], p1 = pv[1], p2 = pv[2];
  {
    const bool own = (K < 8) && (t == K);
    float cur = getel<K>(a0, b0, c0);
    float f = own ? 0.0f : cur;
    setel<K>(a0, b0, c0, own ? cur : 0.0f);
    ELIM(f, a0, b0, c0);
  }
  {
    const bool own = (K >= 8) && (t == K - 8);
    float cur = getel<K>(a1, b1, c1);
    float f = own ? 0.0f : cur;
    setel<K>(a1, b1, c1, own ? cur : 0.0f);
    ELIM(f, a1, b1, c1);
  }
  WFENCE();
}

template<int K>
__device__ __forceinline__ void rgj_all(float4& a0, float4& b0, float4& c0,
                                        float4& a1, float4& b1, float4& c1,
                                        float* piv, int t) {
  rgj_step<K>(a0, b0, c0, a1, b1, c1, piv, t);
  if constexpr (K < 11) rgj_all<K + 1>(a0, b0, c0, a1, b1, c1, piv, t);
}

// ---- merged Gram rows (HtH) for rows t and i1, into registers -------------
__device__ __forceinline__ void gram_rows(const float* myH, int t, int i1,
    float4& a0, float4& b0, float4& c0, float4& a1, float4& b1, float4& c1) {
  a0 = make_float4(0.f, 0.f, 0.f, 0.f);
  b0 = a0; c0 = a0; a1 = a0; b1 = a0; c1 = a0;
#pragma unroll
  for (int k = 0; k < 24; ++k) {
    const float4* hk = (const float4*)(myH + k * 12);
    float4 h0 = hk[0], h1 = hk[1], h2 = hk[2];
    float f0 = myH[k * 12 + t];
    float f1 = myH[k * 12 + i1];
    VFMA(a0, f0, h0); VFMA(b0, f0, h1); VFMA(c0, f0, h2);
    VFMA(a1, f1, h0); VFMA(b1, f1, h1); VFMA(c1, f1, h2);
  }
}

// ---- one permuted Fm slot (all 3 rows at once, shared H[c] load) ----------
// Fm symmetric: Fm[r][c] = delta - <H[c,:], W[:,r]>, W[:,r] = Ginv * H[r,:].
template<int g, int k>
__device__ __forceinline__ void slot3(const float* myH, int t,
    const float4* W0, const float4* W1, const float4* W2,
    float4* P0, float4* P1, float4* P2) {
  const int c = 3 * (t ^ GMAP[g]) + k;
  const float4* hc = (const float4*)(myH + c * 12);
  float4 h0 = hc[0], h1 = hc[1], h2 = hc[2];
  float d0 = 0.f, d1 = 0.f, d2 = 0.f;
  FMA4(d0, h0, W0[0]); FMA4(d0, h1, W0[1]); FMA4(d0, h2, W0[2]);
  FMA4(d1, h0, W1[0]); FMA4(d1, h1, W1[1]); FMA4(d1, h2, W1[2]);
  FMA4(d2, h0, W2[0]); FMA4(d2, h1, W2[1]); FMA4(d2, h2, W2[2]);
  constexpr int S = 3 * g + k;
  putS<S>(P0, ((g == 0 && k == 0) ? 1.0f : 0.0f) - d0);
  putS<S>(P1, ((g == 0 && k == 1) ? 1.0f : 0.0f) - d1);
  putS<S>(P2, ((g == 0 && k == 2) ? 1.0f : 0.0f) - d2);
}

// b element in gather-permuted slot S
template<int S>
__device__ __forceinline__ float bgat(const float* bB, int t) {
  constexpr int g = S / 3, k = S % 3;
  return bB[3 * (t ^ GMAP[g]) + k];
}

__global__ __attribute__((amdgpu_flat_work_group_size(BLOCK, BLOCK),
                          amdgpu_waves_per_eu(2, 4)))
void pdhg_kernel(const float* __restrict__ P, const float* __restrict__ q,
                 const float* __restrict__ H, const float* __restrict__ b,
                 const float* __restrict__ cf, const int* __restrict__ itp,
                 float* __restrict__ out, int Btot) {
  __shared__ __align__(16) float sH[EPB * HS];
  __shared__ __align__(16) float sGi[EPB * GS];
  __shared__ __align__(16) float sB[EPB * SS];
  __shared__ __align__(16) float sAux[EPB * SS];

  const int tid  = threadIdx.x;
  const int wq   = tid >> 6;          // wave 0..3 — fully independent
  const int lane = tid & 63;
  const int e    = wq * 8 + (lane >> 3);
  const int t    = lane & 7;
  const int env  = blockIdx.x * EPB + e;
  const int envW0 = blockIdx.x * EPB + wq * 8;
  const int niter = itp[0];
  const int r0w = 3 * t;
  const int i1 = (t < 4) ? t + 8 : t;   // second owned row (safe alias for t>=4)

  // ---- PER-WAVE float4 staging of this wave's 8 envs: H, P, q, b ----
  {
    const float4* gH = (const float4*)(H + (size_t)envW0 * 288);
#pragma unroll
    for (int rep = 0; rep < 9; ++rep) {
      int i = lane + rep * 64;
      int ee = i / 72, off = i - ee * 72;
      *(float4*)&sH[(wq * 8 + ee) * HS + off * 4] = gH[i];
    }
    const float4* gP = (const float4*)(P + (size_t)envW0 * 144);
#pragma unroll
    for (int rep = 0; rep < 4; ++rep) {
      int i = lane + rep * 64;
      int ee = i / 36, off = i - ee * 36;
      *(float4*)&sGi[(wq * 8 + ee) * GS + off * 4] = gP[i];
    }
    { int i = lane + 256; if (lane < 32) {
        int ee = i / 36, off = i - ee * 36;
        *(float4*)&sGi[(wq * 8 + ee) * GS + off * 4] = gP[i]; } }
    const float4* gq = (const float4*)(q + (size_t)envW0 * 12);
    if (lane < 24) {
      int ee = lane / 3, off = lane - ee * 3;
      *(float4*)&sAux[(wq * 8 + ee) * SS + off * 4] = gq[lane];
    }
    const float4* gb = (const float4*)(b + (size_t)envW0 * 24);
    if (lane < 48) {
      int ee = lane / 6, off = lane - ee * 6;
      *(float4*)&sB[(wq * 8 + ee) * SS + off * 4] = gb[lane];
    }
  }
  WFENCE();

  const float* myH = &sH[e * HS];
  float* giB  = &sGi[e * GS];
  float* auxB = &sAux[e * SS];
  float* bBm  = &sB[e * SS];
  const float* bB = bBm;

  // ---- G = P + HtH in registers (rows t, i1); invert in place -------------
  float4 g0a, g0b, g0c, g1a, g1b, g1c;
  gram_rows(myH, t, i1, g0a, g0b, g0c, g1a, g1b, g1c);
  {
    const float4* p0 = (const float4*)(giB + t * 12);
    const float4* p1 = (const float4*)(giB + i1 * 12);
    float4 q0 = p0[0], q1 = p0[1], q2 = p0[2];
    float4 r0 = p1[0], r1 = p1[1], r2 = p1[2];
    ADD4(g0a, q0); ADD4(g0b, q1); ADD4(g0c, q2);
    ADD4(g1a, r0); ADD4(g1b, r1); ADD4(g1c, r2);
  }
  // pivot buffer: aux[12..23] (free until y is written)
  rgj_all<0>(g0a, g0b, g0c, g1a, g1b, g1c, auxB + 12, t);

  // ---- publish Ginv to LDS (overwrites staged P) + y = Ginv*q -------------
  {
    float4* w0 = (float4*)(giB + t * 12);
    w0[0] = g0a; w0[1] = g0b; w0[2] = g0c;
    if (t < 4) {
      float4* w1 = (float4*)(giB + (t + 8) * 12);
      w1[0] = g1a; w1[1] = g1b; w1[2] = g1c;
    }
  }
  float y0 = dot12(g0a, g0b, g0c, auxB);
  float y1 = dot12(g1a, g1b, g1c, auxB);
  WFENCE();
  auxB[12 + t] = y0;
  if (t < 4) auxB[20 + t] = y1;
  WFENCE();

  // ---- own H rows to regs; u = H*y (own rows) -----------------------------
  float4 hr0[3], hr1[3], hr2[3];
  { const float4* p = (const float4*)(myH + (r0w + 0) * 12); hr0[0]=p[0]; hr0[1]=p[1]; hr0[2]=p[2]; }
  { const float4* p = (const float4*)(myH + (r0w + 1) * 12); hr1[0]=p[0]; hr1[1]=p[1]; hr1[2]=p[2]; }
  { const float4* p = (const float4*)(myH + (r0w + 2) * 12); hr2[0]=p[0]; hr2[1]=p[1]; hr2[2]=p[2]; }
  float u0, u1, u2;
  {
    const float4* y4 = (const float4*)(auxB + 12);
    float4 ya = y4[0], yb = y4[1], yc = y4[2];
    u0 = 0.f; FMA4(u0, hr0[0], ya); FMA4(u0, hr0[1], yb); FMA4(u0, hr0[2], yc);
    u1 = 0.f; FMA4(u1, hr1[0], ya); FMA4(u1, hr1[1], yb); FMA4(u1, hr1[2], yc);
    u2 = 0.f; FMA4(u2, hr2[0], ya); FMA4(u2, hr2[1], yb); FMA4(u2, hr2[2], yc);
  }

  // ---- W[:,r] = Ginv * H[r,:] for the 3 own rows (Ginv rows read ONCE) ----
  float4 W0[3], W1[3], W2[3];
  W0[0] = make_float4(0.f,0.f,0.f,0.f); W0[1] = W0[0]; W0[2] = W0[0];
  W1[0] = W0[0]; W1[1] = W0[0]; W1[2] = W0[0];
  W2[0] = W0[0]; W2[1] = W0[0]; W2[2] = W0[0];
#define ACC_W(c, EX)                                                   \
  { const float4* g4 = (const float4*)(giB + (c) * 12);                \
    float4 r0 = g4[0], r1 = g4[1], r2 = g4[2];                         \
    float k0 = hr0[(c) >> 2].EX, k1 = hr1[(c) >> 2].EX, k2 = hr2[(c) >> 2].EX; \
    VFMA(W0[0], k0, r0); VFMA(W0[1], k0, r1); VFMA(W0[2], k0, r2);     \
    VFMA(W1[0], k1, r0); VFMA(W1[1], k1, r1); VFMA(W1[2], k1, r2);     \
    VFMA(W2[0], k2, r0); VFMA(W2[1], k2, r1); VFMA(W2[2], k2, r2); }
  ACC_W(0, x) ACC_W(1, y) ACC_W(2,  z) ACC_W(3,  w)
  ACC_W(4, x) ACC_W(5, y) ACC_W(6,  z) ACC_W(7,  w)
  ACC_W(8, x) ACC_W(9, y) ACC_W(10, z) ACC_W(11, w)
#undef ACC_W

  // ---- column-PERMUTED Fm rows, one pass sharing H[c] loads ---------------
  float4 Pm0[6], Pm1[6], Pm2[6];
#define SL(g, k) slot3<g, k>(myH, t, W0, W1, W2, Pm0, Pm1, Pm2);
  SL(0,0) SL(0,1) SL(0,2)  SL(1,0) SL(1,1) SL(1,2)
  SL(2,0) SL(2,1) SL(2,2)  SL(3,0) SL(3,1) SL(3,2)
  SL(4,0) SL(4,1) SL(4,2)  SL(5,0) SL(5,1) SL(5,2)
  SL(6,0) SL(6,1) SL(6,2)  SL(7,0) SL(7,1) SL(7,2)
#undef SL

  // ---- mu = H*y - Fm*b (b gathered permuted) ------------------------------
  float mu0, mu1, mu2;
  {
    float4 bg0 = make_float4(bgat<0>(bB,t),  bgat<1>(bB,t),  bgat<2>(bB,t),  bgat<3>(bB,t));
    float4 bg1 = make_float4(bgat<4>(bB,t),  bgat<5>(bB,t),  bgat<6>(bB,t),  bgat<7>(bB,t));
    float4 bg2 = make_float4(bgat<8>(bB,t),  bgat<9>(bB,t),  bgat<10>(bB,t), bgat<11>(bB,t));
    float4 bg3 = make_float4(bgat<12>(bB,t), bgat<13>(bB,t), bgat<14>(bB,t), bgat<15>(bB,t));
    float4 bg4 = make_float4(bgat<16>(bB,t), bgat<17>(bB,t), bgat<18>(bB,t), bgat<19>(bB,t));
    float4 bg5 = make_float4(bgat<20>(bB,t), bgat<21>(bB,t), bgat<22>(bB,t), bgat<23>(bB,t));
    float d0 = 0.f, d1 = 0.f, d2 = 0.f;
    FMA4(d0, Pm0[0], bg0); FMA4(d1, Pm1[0], bg0); FMA4(d2, Pm2[0], bg0);
    FMA4(d0, Pm0[1], bg1); FMA4(d1, Pm1[1], bg1); FMA4(d2, Pm2[1], bg1);
    FMA4(d0, Pm0[2], bg2); FMA4(d1, Pm1[2], bg2); FMA4(d2, Pm2[2], bg2);
    FMA4(d0, Pm0[3], bg3); FMA4(d1, Pm1[3], bg3); FMA4(d2, Pm2[3], bg3);
    FMA4(d0, Pm0[4], bg4); FMA4(d1, Pm1[4], bg4); FMA4(d2, Pm2[4], bg4);
    FMA4(d0, Pm0[5], bg5); FMA4(d1, Pm1[5], bg5); FMA4(d2, Pm2[5], bg5);
    mu0 = u0 - d0;
    mu1 = u1 - d1;
    mu2 = u2 - d2;
  }
  float cfr0 = cf[(size_t)env * 24 + r0w];
  float cfr1 = cf[(size_t)env * 24 + r0w + 1];
  float cfr2 = cf[(size_t)env * 24 + r0w + 2];

  // ---- iterations: 21-op DPP all-gather + 72 row-FMAs, branchless proj ----
  const float plo  = (t < 4) ? -3.0e38f : -10.0f;
  const float phi  = (t < 4) ?  3.0e38f :  10.0f;
  const float pthr = (t < 4) ? 0.0f     : -3.0e38f;
  float l0 = 0.f, l1 = 0.f, l2 = 0.f, z0 = 0.f, z1 = 0.f, z2 = 0.f;
  for (int it = 0; it < niter; ++it) {
    float s0 = l0 + z0, s1 = l1 + z1, s2 = l2 + z2;
    // all-gather: slots [t, t^1, t^2, t^3, t^7, t^6, t^5, t^4] (= GMAP order)
    float g3  = dppv<DPP_XOR1>(s0), g4  = dppv<DPP_XOR1>(s1), g5  = dppv<DPP_XOR1>(s2);
    float g6  = dppv<DPP_XOR2>(s0), g7  = dppv<DPP_XOR2>(s1), g8  = dppv<DPP_XOR2>(s2);
    float g9  = dppv<DPP_XOR2>(g3), g10 = dppv<DPP_XOR2>(g4), g11 = dppv<DPP_XOR2>(g5);
    float g12 = dppv<DPP_HMIR>(s0), g13 = dppv<DPP_HMIR>(s1), g14 = dppv<DPP_HMIR>(s2);
    float g15 = dppv<DPP_HMIR>(g3), g16 = dppv<DPP_HMIR>(g4), g17 = dppv<DPP_HMIR>(g5);
    float g18 = dppv<DPP_HMIR>(g6), g19 = dppv<DPP_HMIR>(g7), g20 = dppv<DPP_HMIR>(g8);
    float g21 = dppv<DPP_HMIR>(g9), g22 = dppv<DPP_HMIR>(g10), g23 = dppv<DPP_HMIR>(g11);
    float4 v0 = make_float4(s0,  s1,  s2,  g3);
    float4 v1 = make_float4(g4,  g5,  g6,  g7);
    float4 v2 = make_float4(g8,  g9,  g10, g11);
    float4 v3 = make_float4(g12, g13, g14, g15);
    float4 v4 = make_float4(g16, g17, g18, g19);
    float4 v5 = make_float4(g20, g21, g22, g23);
    // two chains per row
    float a0 = mu0, a1 = mu1, a2 = mu2, b0 = 0.f, b1 = 0.f, b2 = 0.f;
    FMA4(a0, Pm0[0], v0); FMA4(a1, Pm1[0], v0); FMA4(a2, Pm2[0], v0);
    FMA4(a0, Pm0[1], v1); FMA4(a1, Pm1[1], v1); FMA4(a2, Pm2[1], v1);
    FMA4(a0, Pm0[2], v2); FMA4(a1, Pm1[2], v2); FMA4(a2, Pm2[2], v2);
    FMA4(b0, Pm0[3], v3); FMA4(b1, Pm1[3], v3); FMA4(b2, Pm2[3], v3);
    FMA4(b0, Pm0[4], v4); FMA4(b1, Pm1[4], v4); FMA4(b2, Pm2[4], v4);
    FMA4(b0, Pm0[5], v5); FMA4(b1, Pm1[5], v5); FMA4(b2, Pm2[5], v5);
    float w0 = a0 + b0, w1 = a1 + b1, w2 = a2 + b2;
    float zp0 = fmaf(-2.0f, w0, s0);
    float zp1 = fmaf(-2.0f, w1, s1);
    float zp2 = fmaf(-2.0f, w2, s2);
    l0 = w0; l1 = w1; l2 = w2;
    // cone lanes (t<4): no clamp, gate on zp2>0; box lanes: clamp, gate true
    bool gt = zp2 > pthr;
    float e0 = gt ? cfr0 : 0.0f;
    float e1 = gt ? cfr1 : 0.0f;
    float e2 = gt ? cfr2 : 0.0f;
    z0 = __builtin_amdgcn_fmed3f(zp0, plo, phi) * e0;
    z1 = __builtin_amdgcn_fmed3f(zp1, plo, phi) * e1;
    z2 = __builtin_amdgcn_fmed3f(zp2, plo, phi) * e2;
  }

  // ---- outputs: lz, then x = (HtH)^-1 Ht (z - b) --------------------------
  float* xout  = out;
  float* lzout = out + (size_t)Btot * 12;
  lzout[(size_t)env * 48 + r0w]          = l0;
  lzout[(size_t)env * 48 + r0w + 1]      = l1;
  lzout[(size_t)env * 48 + r0w + 2]      = l2;
  lzout[(size_t)env * 48 + 24 + r0w]     = z0;
  lzout[(size_t)env * 48 + 24 + r0w + 1] = z1;
  lzout[(size_t)env * 48 + 24 + r0w + 2] = z2;

  float bo0 = bB[r0w];
  float bo1 = bB[r0w + 1];
  float bo2 = bB[r0w + 2];
  WFENCE();
  auxB[r0w]     = z0 - bo0;
  auxB[r0w + 1] = z1 - bo1;
  auxB[r0w + 2] = z2 - bo2;
  WFENCE();

  // rv = Ht (z - b), both owned columns in one pass, vectorized aux reads
  float rv0 = 0.f, rv8 = 0.f;
  {
    const float4* a4 = (const float4*)auxB;
    float4 au0 = a4[0], au1 = a4[1], au2 = a4[2], au3 = a4[3], au4 = a4[4], au5 = a4[5];
#define RVS(k, AV) { rv0 = fmaf(myH[(k) * 12 + t],  (AV), rv0);   \
                     rv8 = fmaf(myH[(k) * 12 + i1], (AV), rv8); }
    RVS(0,  au0.x) RVS(1,  au0.y) RVS(2,  au0.z) RVS(3,  au0.w)
    RVS(4,  au1.x) RVS(5,  au1.y) RVS(6,  au1.z) RVS(7,  au1.w)
    RVS(8,  au2.x) RVS(9,  au2.y) RVS(10, au2.z) RVS(11, au2.w)
    RVS(12, au3.x) RVS(13, au3.y) RVS(14, au3.z) RVS(15, au3.w)
    RVS(16, au4.x) RVS(17, au4.y) RVS(18, au4.z) RVS(19, au4.w)
    RVS(20, au5.x) RVS(21, au5.y) RVS(22, au5.z) RVS(23, au5.w)
#undef RVS
  }

  // second Gram (no P) + register GJ; pivot buffer reuses sB[0..11]
  gram_rows(myH, t, i1, g0a, g0b, g0c, g1a, g1b, g1c);
  WFENCE();
  auxB[t] = rv0;
  if (t < 4) auxB[t + 8] = rv8;
  WFENCE();
  rgj_all<0>(g0a, g0b, g0c, g1a, g1b, g1c, bBm, t);

  xout[(size_t)env * 12 + t] = dot12(g0a, g0b, g0c, auxB);
  if (t < 4)
    xout[(size_t)env * 12 + t + 8] = dot12(g1a, g1b, g1c, auxB);
}

extern "C" void kernel_launch(void* const* d_in, const int* in_sizes, int n_in,
                              void* d_out, int out_size, void* d_ws, size_t ws_size,
                              hipStream_t stream) {
  const float* P  = (const float*)d_in[0];
  const float* q  = (const float*)d_in[1];
  const float* H  = (const float*)d_in[2];
  const float* b  = (const float*)d_in[3];
  const float* cf = (const float*)d_in[4];
  const int*   it = (const int*)d_in[5];
  float* out = (float*)d_out;
  const int B = in_sizes[1] / 12;       // q is [B,12]
  const int grid = B / EPB;             // 16384/32 = 512 blocks
  pdhg_kernel<<<grid, BLOCK, 0, stream>>>(P, q, H, b, cf, it, out, B);
}

// Round 2
// 144.941 us; speedup vs baseline: 1.3276x; 1.3276x over previous
//
#include <hip/hip_runtime.h>

#define EPB 32          // envs per block (8 per wave)
#define BLOCK 256       // 4 independent waves; env = 8 lanes, wave-internal
#define HS 292          // H LDS stride (288 + 4)
#define GS 148          // G/Ginv LDS stride (144 + 4)
#define SS 28           // b / aux stride (24 + 4)

#define WFENCE() __builtin_amdgcn_wave_barrier()   // compiler fence, 0 instr

#define DPP_XOR1 0xB1   // quad_perm [1,0,3,2]  : lane ^= 1
#define DPP_XOR2 0x4E   // quad_perm [2,3,0,1]  : lane ^= 2
#define DPP_HMIR 0x141  // row_half_mirror      : lane ^= 7 (within 8)

// gather slot-group g (0..7) holds the s-triple of lane (t ^ GMAP[g]):
// slots built as [own, xor1, xor2(own,xor1), hmir(first 12)]
constexpr int GMAP[8] = {0, 1, 2, 3, 7, 6, 5, 4};

// acc += dot(f4, s4)
#define FMA4(acc, f, s)                                         \
  acc = fmaf((f).x, (s).x,                                      \
        fmaf((f).y, (s).y,                                      \
        fmaf((f).z, (s).z,                                      \
        fmaf((f).w, (s).w, (acc)))))

// acc4 += s * v4
#define VFMA(acc, s, v)                                         \
  { (acc).x = fmaf((s), (v).x, (acc).x);                        \
    (acc).y = fmaf((s), (v).y, (acc).y);                        \
    (acc).z = fmaf((s), (v).z, (acc).z);                        \
    (acc).w = fmaf((s), (v).w, (acc).w); }

#define ADD4(A, B) { (A).x += (B).x; (A).y += (B).y; (A).z += (B).z; (A).w += (B).w; }

template<int CTRL>
__device__ __forceinline__ float dppv(float v) {
  return __int_as_float(__builtin_amdgcn_update_dpp(
      0, __float_as_int(v), CTRL, 0xF, 0xF, true));
}

template<int K>
__device__ __forceinline__ float getel(const float4& a, const float4& b, const float4& c) {
  if constexpr (K == 0) return a.x; else if constexpr (K == 1) return a.y;
  else if constexpr (K == 2) return a.z; else if constexpr (K == 3) return a.w;
  else if constexpr (K == 4) return b.x; else if constexpr (K == 5) return b.y;
  else if constexpr (K == 6) return b.z; else if constexpr (K == 7) return b.w;
  else if constexpr (K == 8) return c.x; else if constexpr (K == 9) return c.y;
  else if constexpr (K == 10) return c.z; else return c.w;
}
template<int K>
__device__ __forceinline__ void setel(float4& a, float4& b, float4& c, float v) {
  if constexpr (K == 0) a.x = v; else if constexpr (K == 1) a.y = v;
  else if constexpr (K == 2) a.z = v; else if constexpr (K == 3) a.w = v;
  else if constexpr (K == 4) b.x = v; else if constexpr (K == 5) b.y = v;
  else if constexpr (K == 6) b.z = v; else if constexpr (K == 7) b.w = v;
  else if constexpr (K == 8) c.x = v; else if constexpr (K == 9) c.y = v;
  else if constexpr (K == 10) c.z = v; else c.w = v;
}

// write scalar into slot S (0..23) of a float4[6] row (all-constant indices)
template<int S>
__device__ __forceinline__ void putS(float4* m, float v) {
  constexpr int Q = S >> 2, R = S & 3;
  if constexpr (R == 0) m[Q].x = v;
  else if constexpr (R == 1) m[Q].y = v;
  else if constexpr (R == 2) m[Q].z = v;
  else m[Q].w = v;
}

__device__ __forceinline__ float dot12(float4 a0, float4 a1, float4 a2,
                                       const float* p) {
  const float4* p4 = (const float4*)p;
  float4 b0 = p4[0], b1 = p4[1], b2 = p4[2];
  float acc = 0.f;
  FMA4(acc, a0, b0); FMA4(acc, a1, b1); FMA4(acc, a2, b2);
  return acc;
}

// ---- register-resident Gauss-Jordan (SPD, no pivoting) --------------------
// Thread keeps rows t and t+8 (i1) in registers; only the pivot row goes
// through LDS (3 stores by owner, 3 broadcast loads by everyone).
template<int K>
__device__ __forceinline__ void pivot_pub(float4& a, float4& b, float4& c, float* piv) {
  float ip = 1.0f / getel<K>(a, b, c);
  setel<K>(a, b, c, 1.0f);
  a.x *= ip; a.y *= ip; a.z *= ip; a.w *= ip;
  b.x *= ip; b.y *= ip; b.z *= ip; b.w *= ip;
  c.x *= ip; c.y *= ip; c.z *= ip; c.w *= ip;
  float4* pv = (float4*)piv;
  pv[0] = a; pv[1] = b; pv[2] = c;
}

#define ELIM(f, A, B, C)                                              \
  { (A).x = fmaf(-(f), p0.x, (A).x); (A).y = fmaf(-(f), p0.y, (A).y); \
    (A).z = fmaf(-(f), p0.z, (A).z); (A).w = fmaf(-(f), p0.w, (A).w); \
    (B).x = fmaf(-(f), p1.x, (B).x); (B).y = fmaf(-(f), p1.y, (B).y); \
    (B).z = fmaf(-(f), p1.z, (B).z); (B).w = fmaf(-(f), p1.w, (B).w); \
    (C).x = fmaf(-(f), p2.x, (C).x); (C).y = fmaf(-(f), p2.y, (C).y); \
    (C).z = fmaf(-(f), p2.z, (C).z); (C).w = fmaf(-(f), p2.w, (C).w); }

template<int K>
__device__ __forceinline__ void rgj_step(float4& a0, float4& b0, float4& c0,
                                         float4& a1, float4& b1, float4& c1,
                                         float* piv, int t) {
  if constexpr (K < 8) {
    if (t == K) pivot_pub<K>(a0, b0, c0, piv);
  } else {
    if (t == K - 8) pivot_pub<K>(a1, b1, c1, piv);
  }
  WFENCE();
  const float4* pv = (const float4*)piv;
  float4 p0 = pv[0], p1 = pv[1], p2 = pv[2];
  {
    const bool own = (K < 8) && (t == K);
    float cur = getel<K>(a0, b0, c0);
    float f = own ? 0.0f : cur;
    setel<K>(a0, b0, c0, own ? cur : 0.0f);
    ELIM(f, a0, b0, c0);
  }
  {
    const bool own = (K >= 8) && (t == K - 8);
    float cur = getel<K>(a1, b1, c1);
    float f = own ? 0.0f : cur;
    setel<K>(a1, b1, c1, own ? cur : 0.0f);
    ELIM(f, a1, b1, c1);
  }
  WFENCE();
}

template<int K>
__device__ __forceinline__ void rgj_all(float4& a0, float4& b0, float4& c0,
                                        float4& a1, float4& b1, float4& c1,
                                        float* piv, int t) {
  rgj_step<K>(a0, b0, c0, a1, b1, c1, piv, t);
  if constexpr (K < 11) rgj_all<K + 1>(a0, b0, c0, a1, b1, c1, piv, t);
}

// ---- merged Gram rows (HtH) for rows t and i1, into registers -------------
__device__ __forceinline__ void gram_rows(const float* myH, int t, int i1,
    float4& a0, float4& b0, float4& c0, float4& a1, float4& b1, float4& c1) {
  a0 = make_float4(0.f, 0.f, 0.f, 0.f);
  b0 = a0; c0 = a0; a1 = a0; b1 = a0; c1 = a0;
#pragma unroll
  for (int k = 0; k < 24; ++k) {
    const float4* hk = (const float4*)(myH + k * 12);
    float4 h0 = hk[0], h1 = hk[1], h2 = hk[2];
    float f0 = myH[k * 12 + t];
    float f1 = myH[k * 12 + i1];
    VFMA(a0, f0, h0); VFMA(b0, f0, h1); VFMA(c0, f0, h2);
    VFMA(a1, f1, h0); VFMA(b1, f1, h1); VFMA(c1, f1, h2);
  }
}

// ---- one permuted Fm slot (all 3 rows at once, shared H[c] load) ----------
// Fm symmetric: Fm[r][c] = delta - <H[c,:], W[:,r]>, W[:,r] = Ginv * H[r,:].
template<int g, int k>
__device__ __forceinline__ void slot3(const float* myH, int t,
    const float4* W0, const float4* W1, const float4* W2,
    float4* P0, float4* P1, float4* P2) {
  const int c = 3 * (t ^ GMAP[g]) + k;
  const float4* hc = (const float4*)(myH + c * 12);
  float4 h0 = hc[0], h1 = hc[1], h2 = hc[2];
  float d0 = 0.f, d1 = 0.f, d2 = 0.f;
  FMA4(d0, h0, W0[0]); FMA4(d0, h1, W0[1]); FMA4(d0, h2, W0[2]);
  FMA4(d1, h0, W1[0]); FMA4(d1, h1, W1[1]); FMA4(d1, h2, W1[2]);
  FMA4(d2, h0, W2[0]); FMA4(d2, h1, W2[1]); FMA4(d2, h2, W2[2]);
  constexpr int S = 3 * g + k;
  putS<S>(P0, ((g == 0 && k == 0) ? 1.0f : 0.0f) - d0);
  putS<S>(P1, ((g == 0 && k == 1) ? 1.0f : 0.0f) - d1);
  putS<S>(P2, ((g == 0 && k == 2) ? 1.0f : 0.0f) - d2);
}

// b element in gather-permuted slot S
template<int S>
__device__ __forceinline__ float bgat(const float* bB, int t) {
  constexpr int g = S / 3, k = S % 3;
  return bB[3 * (t ^ GMAP[g]) + k];
}

__global__ __attribute__((amdgpu_flat_work_group_size(BLOCK, BLOCK),
                          amdgpu_waves_per_eu(1, 4)))
void pdhg_kernel(const float* __restrict__ P, const float* __restrict__ q,
                 const float* __restrict__ H, const float* __restrict__ b,
                 const float* __restrict__ cf, const int* __restrict__ itp,
                 float* __restrict__ out, int Btot) {
  __shared__ __align__(16) float sH[EPB * HS];
  __shared__ __align__(16) float sGi[EPB * GS];
  __shared__ __align__(16) float sB[EPB * SS];
  __shared__ __align__(16) float sAux[EPB * SS];

  const int tid  = threadIdx.x;
  const int wq   = tid >> 6;          // wave 0..3 — fully independent
  const int lane = tid & 63;
  const int e    = wq * 8 + (lane >> 3);
  const int t    = lane & 7;
  const int env  = blockIdx.x * EPB + e;
  const int envW0 = blockIdx.x * EPB + wq * 8;
  const int niter = itp[0];
  const int r0w = 3 * t;
  const int i1 = (t < 4) ? t + 8 : t;   // second owned row (safe alias for t>=4)

  // ---- PER-WAVE float4 staging of this wave's 8 envs: H, P, q, b ----
  {
    const float4* gH = (const float4*)(H + (size_t)envW0 * 288);
#pragma unroll
    for (int rep = 0; rep < 9; ++rep) {
      int i = lane + rep * 64;
      int ee = i / 72, off = i - ee * 72;
      *(float4*)&sH[(wq * 8 + ee) * HS + off * 4] = gH[i];
    }
    const float4* gP = (const float4*)(P + (size_t)envW0 * 144);
#pragma unroll
    for (int rep = 0; rep < 4; ++rep) {
      int i = lane + rep * 64;
      int ee = i / 36, off = i - ee * 36;
      *(float4*)&sGi[(wq * 8 + ee) * GS + off * 4] = gP[i];
    }
    { int i = lane + 256; if (lane < 32) {
        int ee = i / 36, off = i - ee * 36;
        *(float4*)&sGi[(wq * 8 + ee) * GS + off * 4] = gP[i]; } }
    const float4* gq = (const float4*)(q + (size_t)envW0 * 12);
    if (lane < 24) {
      int ee = lane / 3, off = lane - ee * 3;
      *(float4*)&sAux[(wq * 8 + ee) * SS + off * 4] = gq[lane];
    }
    const float4* gb = (const float4*)(b + (size_t)envW0 * 24);
    if (lane < 48) {
      int ee = lane / 6, off = lane - ee * 6;
      *(float4*)&sB[(wq * 8 + ee) * SS + off * 4] = gb[lane];
    }
  }
  WFENCE();

  const float* myH = &sH[e * HS];
  float* giB  = &sGi[e * GS];
  float* auxB = &sAux[e * SS];
  float* bBm  = &sB[e * SS];
  const float* bB = bBm;

  // ---- G = P + HtH in registers (rows t, i1); invert in place -------------
  float4 g0a, g0b, g0c, g1a, g1b, g1c;
  gram_rows(myH, t, i1, g0a, g0b, g0c, g1a, g1b, g1c);
  {
    const float4* p0 = (const float4*)(giB + t * 12);
    const float4* p1 = (const float4*)(giB + i1 * 12);
    float4 q0 = p0[0], q1 = p0[1], q2 = p0[2];
    float4 r0 = p1[0], r1 = p1[1], r2 = p1[2];
    ADD4(g0a, q0); ADD4(g0b, q1); ADD4(g0c, q2);
    ADD4(g1a, r0); ADD4(g1b, r1); ADD4(g1c, r2);
  }
  // pivot buffer: aux[12..23] (free until y is written)
  rgj_all<0>(g0a, g0b, g0c, g1a, g1b, g1c, auxB + 12, t);

  // ---- publish Ginv to LDS (overwrites staged P) + y = Ginv*q -------------
  {
    float4* w0 = (float4*)(giB + t * 12);
    w0[0] = g0a; w0[1] = g0b; w0[2] = g0c;
    if (t < 4) {
      float4* w1 = (float4*)(giB + (t + 8) * 12);
      w1[0] = g1a; w1[1] = g1b; w1[2] = g1c;
    }
  }
  float y0 = dot12(g0a, g0b, g0c, auxB);
  float y1 = dot12(g1a, g1b, g1c, auxB);
  WFENCE();
  auxB[12 + t] = y0;
  if (t < 4) auxB[20 + t] = y1;
  WFENCE();

  // ---- own H rows to regs; u = H*y (own rows) -----------------------------
  float4 hr0[3], hr1[3], hr2[3];
  { const float4* p = (const float4*)(myH + (r0w + 0) * 12); hr0[0]=p[0]; hr0[1]=p[1]; hr0[2]=p[2]; }
  { const float4* p = (const float4*)(myH + (r0w + 1) * 12); hr1[0]=p[0]; hr1[1]=p[1]; hr1[2]=p[2]; }
  { const float4* p = (const float4*)(myH + (r0w + 2) * 12); hr2[0]=p[0]; hr2[1]=p[1]; hr2[2]=p[2]; }
  float u0, u1, u2;
  {
    const float4* y4 = (const float4*)(auxB + 12);
    float4 ya = y4[0], yb = y4[1], yc = y4[2];
    u0 = 0.f; FMA4(u0, hr0[0], ya); FMA4(u0, hr0[1], yb); FMA4(u0, hr0[2], yc);
    u1 = 0.f; FMA4(u1, hr1[0], ya); FMA4(u1, hr1[1], yb); FMA4(u1, hr1[2], yc);
    u2 = 0.f; FMA4(u2, hr2[0], ya); FMA4(u2, hr2[1], yb); FMA4(u2, hr2[2], yc);
  }

  // ---- W[:,r] = Ginv * H[r,:] for the 3 own rows (Ginv rows read ONCE) ----
  float4 W0[3], W1[3], W2[3];
  W0[0] = make_float4(0.f,0.f,0.f,0.f); W0[1] = W0[0]; W0[2] = W0[0];
  W1[0] = W0[0]; W1[1] = W0[0]; W1[2] = W0[0];
  W2[0] = W0[0]; W2[1] = W0[0]; W2[2] = W0[0];
#define ACC_W(c, EX)                                                   \
  { const float4* g4 = (const float4*)(giB + (c) * 12);                \
    float4 r0 = g4[0], r1 = g4[1], r2 = g4[2];                         \
    float k0 = hr0[(c) >> 2].EX, k1 = hr1[(c) >> 2].EX, k2 = hr2[(c) >> 2].EX; \
    VFMA(W0[0], k0, r0); VFMA(W0[1], k0, r1); VFMA(W0[2], k0, r2);     \
    VFMA(W1[0], k1, r0); VFMA(W1[1], k1, r1); VFMA(W1[2], k1, r2);     \
    VFMA(W2[0], k2, r0); VFMA(W2[1], k2, r1); VFMA(W2[2], k2, r2); }
  ACC_W(0, x) ACC_W(1, y) ACC_W(2,  z) ACC_W(3,  w)
  ACC_W(4, x) ACC_W(5, y) ACC_W(6,  z) ACC_W(7,  w)
  ACC_W(8, x) ACC_W(9, y) ACC_W(10, z) ACC_W(11, w)
#undef ACC_W

  // ---- column-PERMUTED Fm rows, one pass sharing H[c] loads ---------------
  float4 Pm0[6], Pm1[6], Pm2[6];
#define SL(g, k) slot3<g, k>(myH, t, W0, W1, W2, Pm0, Pm1, Pm2);
  SL(0,0) SL(0,1) SL(0,2)  SL(1,0) SL(1,1) SL(1,2)
  SL(2,0) SL(2,1) SL(2,2)  SL(3,0) SL(3,1) SL(3,2)
  SL(4,0) SL(4,1) SL(4,2)  SL(5,0) SL(5,1) SL(5,2)
  SL(6,0) SL(6,1) SL(6,2)  SL(7,0) SL(7,1) SL(7,2)
#undef SL

  // ---- mu = H*y - Fm*b (b gathered permuted) ------------------------------
  float mu0, mu1, mu2;
  {
    float4 bg0 = make_float4(bgat<0>(bB,t),  bgat<1>(bB,t),  bgat<2>(bB,t),  bgat<3>(bB,t));
    float4 bg1 = make_float4(bgat<4>(bB,t),  bgat<5>(bB,t),  bgat<6>(bB,t),  bgat<7>(bB,t));
    float4 bg2 = make_float4(bgat<8>(bB,t),  bgat<9>(bB,t),  bgat<10>(bB,t), bgat<11>(bB,t));
    float4 bg3 = make_float4(bgat<12>(bB,t), bgat<13>(bB,t), bgat<14>(bB,t), bgat<15>(bB,t));
    float4 bg4 = make_float4(bgat<16>(bB,t), bgat<17>(bB,t), bgat<18>(bB,t), bgat<19>(bB,t));
    float4 bg5 = make_float4(bgat<20>(bB,t), bgat<21>(bB,t), bgat<22>(bB,t), bgat<23>(bB,t));
    float d0 = 0.f, d1 = 0.f, d2 = 0.f;
    FMA4(d0, Pm0[0], bg0); FMA4(d1, Pm1[0], bg0); FMA4(d2, Pm2[0], bg0);
    FMA4(d0, Pm0[1], bg1); FMA4(d1, Pm1[1], bg1); FMA4(d2, Pm2[1], bg1);
    FMA4(d0, Pm0[2], bg2); FMA4(d1, Pm1[2], bg2); FMA4(d2, Pm2[2], bg2);
    FMA4(d0, Pm0[3], bg3); FMA4(d1, Pm1[3], bg3); FMA4(d2, Pm2[3], bg3);
    FMA4(d0, Pm0[4], bg4); FMA4(d1, Pm1[4], bg4); FMA4(d2, Pm2[4], bg4);
    FMA4(d0, Pm0[5], bg5); FMA4(d1, Pm1[5], bg5); FMA4(d2, Pm2[5], bg5);
    mu0 = u0 - d0;
    mu1 = u1 - d1;
    mu2 = u2 - d2;
  }
  float cfr0 = cf[(size_t)env * 24 + r0w];
  float cfr1 = cf[(size_t)env * 24 + r0w + 1];
  float cfr2 = cf[(size_t)env * 24 + r0w + 2];

  // ---- iterations: 21-op DPP all-gather + 72 row-FMAs, branchless proj ----
  const float plo  = (t < 4) ? -3.0e38f : -10.0f;
  const float phi  = (t < 4) ?  3.0e38f :  10.0f;
  const float pthr = (t < 4) ? 0.0f     : -3.0e38f;
  float l0 = 0.f, l1 = 0.f, l2 = 0.f, z0 = 0.f, z1 = 0.f, z2 = 0.f;
  for (int it = 0; it < niter; ++it) {
    float s0 = l0 + z0, s1 = l1 + z1, s2 = l2 + z2;
    // all-gather: slots [t, t^1, t^2, t^3, t^7, t^6, t^5, t^4] (= GMAP order)
    float g3  = dppv<DPP_XOR1>(s0), g4  = dppv<DPP_XOR1>(s1), g5  = dppv<DPP_XOR1>(s2);
    float g6  = dppv<DPP_XOR2>(s0), g7  = dppv<DPP_XOR2>(s1), g8  = dppv<DPP_XOR2>(s2);
    float g9  = dppv<DPP_XOR2>(g3), g10 = dppv<DPP_XOR2>(g4), g11 = dppv<DPP_XOR2>(g5);
    float g12 = dppv<DPP_HMIR>(s0), g13 = dppv<DPP_HMIR>(s1), g14 = dppv<DPP_HMIR>(s2);
    float g15 = dppv<DPP_HMIR>(g3), g16 = dppv<DPP_HMIR>(g4), g17 = dppv<DPP_HMIR>(g5);
    float g18 = dppv<DPP_HMIR>(g6), g19 = dppv<DPP_HMIR>(g7), g20 = dppv<DPP_HMIR>(g8);
    float g21 = dppv<DPP_HMIR>(g9), g22 = dppv<DPP_HMIR>(g10), g23 = dppv<DPP_HMIR>(g11);
    float4 v0 = make_float4(s0,  s1,  s2,  g3);
    float4 v1 = make_float4(g4,  g5,  g6,  g7);
    float4 v2 = make_float4(g8,  g9,  g10, g11);
    float4 v3 = make_float4(g12, g13, g14, g15);
    float4 v4 = make_float4(g16, g17, g18, g19);
    float4 v5 = make_float4(g20, g21, g22, g23);
    // two chains per row
    float a0 = mu0, a1 = mu1, a2 = mu2, b0 = 0.f, b1 = 0.f, b2 = 0.f;
    FMA4(a0, Pm0[0], v0); FMA4(a1, Pm1[0], v0); FMA4(a2, Pm2[0], v0);
    FMA4(a0, Pm0[1], v1); FMA4(a1, Pm1[1], v1); FMA4(a2, Pm2[1], v1);
    FMA4(a0, Pm0[2], v2); FMA4(a1, Pm1[2], v2); FMA4(a2, Pm2[2], v2);
    FMA4(b0, Pm0[3], v3); FMA4(b1, Pm1[3], v3); FMA4(b2, Pm2[3], v3);
    FMA4(b0, Pm0[4], v4); FMA4(b1, Pm1[4], v4); FMA4(b2, Pm2[4], v4);
    FMA4(b0, Pm0[5], v5); FMA4(b1, Pm1[5], v5); FMA4(b2, Pm2[5], v5);
    float w0 = a0 + b0, w1 = a1 + b1, w2 = a2 + b2;
    float zp0 = fmaf(-2.0f, w0, s0);
    float zp1 = fmaf(-2.0f, w1, s1);
    float zp2 = fmaf(-2.0f, w2, s2);
    l0 = w0; l1 = w1; l2 = w2;
    // cone lanes (t<4): no clamp, gate on zp2>0; box lanes: clamp, gate true
    bool gt = zp2 > pthr;
    float e0 = gt ? cfr0 : 0.0f;
    float e1 = gt ? cfr1 : 0.0f;
    float e2 = gt ? cfr2 : 0.0f;
    z0 = __builtin_amdgcn_fmed3f(zp0, plo, phi) * e0;
    z1 = __builtin_amdgcn_fmed3f(zp1, plo, phi) * e1;
    z2 = __builtin_amdgcn_fmed3f(zp2, plo, phi) * e2;
  }

  // ---- outputs: lz, then x = (HtH)^-1 Ht (z - b) --------------------------
  float* xout  = out;
  float* lzout = out + (size_t)Btot * 12;
  lzout[(size_t)env * 48 + r0w]          = l0;
  lzout[(size_t)env * 48 + r0w + 1]      = l1;
  lzout[(size_t)env * 48 + r0w + 2]      = l2;
  lzout[(size_t)env * 48 + 24 + r0w]     = z0;
  lzout[(size_t)env * 48 + 24 + r0w + 1] = z1;
  lzout[(size_t)env * 48 + 24 + r0w + 2] = z2;

  float bo0 = bB[r0w];
  float bo1 = bB[r0w + 1];
  float bo2 = bB[r0w + 2];
  WFENCE();
  auxB[r0w]     = z0 - bo0;
  auxB[r0w + 1] = z1 - bo1;
  auxB[r0w + 2] = z2 - bo2;
  WFENCE();

  // rv = Ht (z - b), both owned columns in one pass, vectorized aux reads
  float rv0 = 0.f, rv8 = 0.f;
  {
    const float4* a4 = (const float4*)auxB;
    float4 au0 = a4[0], au1 = a4[1], au2 = a4[2], au3 = a4[3], au4 = a4[4], au5 = a4[5];
#define RVS(k, AV) { rv0 = fmaf(myH[(k) * 12 + t],  (AV), rv0);   \
                     rv8 = fmaf(myH[(k) * 12 + i1], (AV), rv8); }
    RVS(0,  au0.x) RVS(1,  au0.y) RVS(2,  au0.z) RVS(3,  au0.w)
    RVS(4,  au1.x) RVS(5,  au1.y) RVS(6,  au1.z) RVS(7,  au1.w)
    RVS(8,  au2.x) RVS(9,  au2.y) RVS(10, au2.z) RVS(11, au2.w)
    RVS(12, au3.x) RVS(13, au3.y) RVS(14, au3.z) RVS(15, au3.w)
    RVS(16, au4.x) RVS(17, au4.y) RVS(18, au4.z) RVS(19, au4.w)
    RVS(20, au5.x) RVS(21, au5.y) RVS(22, au5.z) RVS(23, au5.w)
#undef RVS
  }

  // second Gram (no P) + register GJ; pivot buffer reuses sB[0..11]
  gram_rows(myH, t, i1, g0a, g0b, g0c, g1a, g1b, g1c);
  WFENCE();
  auxB[t] = rv0;
  if (t < 4) auxB[t + 8] = rv8;
  WFENCE();
  rgj_all<0>(g0a, g0b, g0c, g1a, g1b, g1c, bBm, t);

  xout[(size_t)env * 12 + t] = dot12(g0a, g0b, g0c, auxB);
  if (t < 4)
    xout[(size_t)env * 12 + t + 8] = dot12(g1a, g1b, g1c, auxB);
}

extern "C" void kernel_launch(void* const* d_in, const int* in_sizes, int n_in,
                              void* d_out, int out_size, void* d_ws, size_t ws_size,
                              hipStream_t stream) {
  const float* P  = (const float*)d_in[0];
  const float* q  = (const float*)d_in[1];
  const float* H  = (const float*)d_in[2];
  const float* b  = (const float*)d_in[3];
  const float* cf = (const float*)d_in[4];
  const int*   it = (const int*)d_in[5];
  float* out = (float*)d_out;
  const int B = in_sizes[1] / 12;       // q is [B,12]
  const int grid = B / EPB;             // 16384/32 = 512 blocks
  pdhg_kernel<<<grid, BLOCK, 0, stream>>>(P, q, H, b, cf, it, out, B);
}

// Round 3
// 139.551 us; speedup vs baseline: 1.3788x; 1.0386x over previous
//
#include <hip/hip_runtime.h>

#define EPB 32          // envs per block (8 per wave)
#define BLOCK 256       // 4 independent waves; env = 8 lanes, wave-internal
#define HS 292          // H LDS stride (288 + 4)
#define GS 148          // G/Ginv LDS stride (144 + 4)
#define SS 28           // b / aux stride (24 + 4)

#define WFENCE() __builtin_amdgcn_wave_barrier()   // compiler fence, 0 instr

#define DPP_XOR1 0xB1   // quad_perm [1,0,3,2]  : lane ^= 1
#define DPP_XOR2 0x4E   // quad_perm [2,3,0,1]  : lane ^= 2
#define DPP_HMIR 0x141  // row_half_mirror      : lane ^= 7 (within 8)

// gather slot-group g (0..7) holds the s-triple of lane (t ^ GMAP[g]):
// slots built as [own, xor1, xor2(own,xor1), hmir(first 12)]
constexpr int GMAP[8] = {0, 1, 2, 3, 7, 6, 5, 4};

typedef float f2 __attribute__((ext_vector_type(2)));

__device__ __forceinline__ f2 pkfma(f2 a, f2 b, f2 c) {
  return __builtin_elementwise_fma(a, b, c);   // -> v_pk_fma_f32 on gfx950
}

// acc += dot(f4, s4)
#define FMA4(acc, f, s)                                         \
  acc = fmaf((f).x, (s).x,                                      \
        fmaf((f).y, (s).y,                                      \
        fmaf((f).z, (s).z,                                      \
        fmaf((f).w, (s).w, (acc)))))

// acc4 += s * v4
#define VFMA(acc, s, v)                                         \
  { (acc).x = fmaf((s), (v).x, (acc).x);                        \
    (acc).y = fmaf((s), (v).y, (acc).y);                        \
    (acc).z = fmaf((s), (v).z, (acc).z);                        \
    (acc).w = fmaf((s), (v).w, (acc).w); }

#define ADD4(A, B) { (A).x += (B).x; (A).y += (B).y; (A).z += (B).z; (A).w += (B).w; }

template<int CTRL>
__device__ __forceinline__ float dppv(float v) {
  return __int_as_float(__builtin_amdgcn_update_dpp(
      0, __float_as_int(v), CTRL, 0xF, 0xF, true));
}

template<int K>
__device__ __forceinline__ float getel(const float4& a, const float4& b, const float4& c) {
  if constexpr (K == 0) return a.x; else if constexpr (K == 1) return a.y;
  else if constexpr (K == 2) return a.z; else if constexpr (K == 3) return a.w;
  else if constexpr (K == 4) return b.x; else if constexpr (K == 5) return b.y;
  else if constexpr (K == 6) return b.z; else if constexpr (K == 7) return b.w;
  else if constexpr (K == 8) return c.x; else if constexpr (K == 9) return c.y;
  else if constexpr (K == 10) return c.z; else return c.w;
}
template<int K>
__device__ __forceinline__ void setel(float4& a, float4& b, float4& c, float v) {
  if constexpr (K == 0) a.x = v; else if constexpr (K == 1) a.y = v;
  else if constexpr (K == 2) a.z = v; else if constexpr (K == 3) a.w = v;
  else if constexpr (K == 4) b.x = v; else if constexpr (K == 5) b.y = v;
  else if constexpr (K == 6) b.z = v; else if constexpr (K == 7) b.w = v;
  else if constexpr (K == 8) c.x = v; else if constexpr (K == 9) c.y = v;
  else if constexpr (K == 10) c.z = v; else c.w = v;
}

// write scalar into slot S (0..23) of an f2[12] row (all-constant indices)
template<int S>
__device__ __forceinline__ void putS2(f2* m, float v) {
  if constexpr ((S & 1) == 0) m[S / 2].x = v; else m[S / 2].y = v;
}

// float4 view of quad Q (slots 4Q..4Q+3) of an f2[12] row — for bit-exact
// reuse of the FMA4 ordering in the mu computation.
#define PMQ(pm, Q) make_float4(pm[2*(Q)].x, pm[2*(Q)].y, pm[2*(Q)+1].x, pm[2*(Q)+1].y)

__device__ __forceinline__ float dot12(float4 a0, float4 a1, float4 a2,
                                       const float* p) {
  const float4* p4 = (const float4*)p;
  float4 b0 = p4[0], b1 = p4[1], b2 = p4[2];
  float acc = 0.f;
  FMA4(acc, a0, b0); FMA4(acc, a1, b1); FMA4(acc, a2, b2);
  return acc;
}

// ---- register-resident Gauss-Jordan (SPD, no pivoting) --------------------
template<int K>
__device__ __forceinline__ void pivot_pub(float4& a, float4& b, float4& c, float* piv) {
  float ip = 1.0f / getel<K>(a, b, c);
  setel<K>(a, b, c, 1.0f);
  a.x *= ip; a.y *= ip; a.z *= ip; a.w *= ip;
  b.x *= ip; b.y *= ip; b.z *= ip; b.w *= ip;
  c.x *= ip; c.y *= ip; c.z *= ip; c.w *= ip;
  float4* pv = (float4*)piv;
  pv[0] = a; pv[1] = b; pv[2] = c;
}

#define ELIM(f, A, B, C)                                              \
  { (A).x = fmaf(-(f), p0.x, (A).x); (A).y = fmaf(-(f), p0.y, (A).y); \
    (A).z = fmaf(-(f), p0.z, (A).z); (A).w = fmaf(-(f), p0.w, (A).w); \
    (B).x = fmaf(-(f), p1.x, (B).x); (B).y = fmaf(-(f), p1.y, (B).y); \
    (B).z = fmaf(-(f), p1.z, (B).z); (B).w = fmaf(-(f), p1.w, (B).w); \
    (C).x = fmaf(-(f), p2.x, (C).x); (C).y = fmaf(-(f), p2.y, (C).y); \
    (C).z = fmaf(-(f), p2.z, (C).z); (C).w = fmaf(-(f), p2.w, (C).w); }

template<int K>
__device__ __forceinline__ void rgj_step(float4& a0, float4& b0, float4& c0,
                                         float4& a1, float4& b1, float4& c1,
                                         float* piv, int t) {
  if constexpr (K < 8) {
    if (t == K) pivot_pub<K>(a0, b0, c0, piv);
  } else {
    if (t == K - 8) pivot_pub<K>(a1, b1, c1, piv);
  }
  WFENCE();
  const float4* pv = (const float4*)piv;
  float4 p0 = pv[0], p1 = pv[1], p2 = pv[2];
  {
    const bool own = (K < 8) && (t == K);
    float cur = getel<K>(a0, b0, c0);
    float f = own ? 0.0f : cur;
    setel<K>(a0, b0, c0, own ? cur : 0.0f);
    ELIM(f, a0, b0, c0);
  }
  {
    const bool own = (K >= 8) && (t == K - 8);
    float cur = getel<K>(a1, b1, c1);
    float f = own ? 0.0f : cur;
    setel<K>(a1, b1, c1, own ? cur : 0.0f);
    ELIM(f, a1, b1, c1);
  }
  WFENCE();
}

template<int K>
__device__ __forceinline__ void rgj_all(float4& a0, float4& b0, float4& c0,
                                        float4& a1, float4& b1, float4& c1,
                                        float* piv, int t) {
  rgj_step<K>(a0, b0, c0, a1, b1, c1, piv, t);
  if constexpr (K < 11) rgj_all<K + 1>(a0, b0, c0, a1, b1, c1, piv, t);
}

// ---- merged Gram rows (HtH) for rows t and i1, into registers -------------
__device__ __forceinline__ void gram_rows(const float* myH, int t, int i1,
    float4& a0, float4& b0, float4& c0, float4& a1, float4& b1, float4& c1) {
  a0 = make_float4(0.f, 0.f, 0.f, 0.f);
  b0 = a0; c0 = a0; a1 = a0; b1 = a0; c1 = a0;
#pragma unroll
  for (int k = 0; k < 24; ++k) {
    const float4* hk = (const float4*)(myH + k * 12);
    float4 h0 = hk[0], h1 = hk[1], h2 = hk[2];
    float f0 = myH[k * 12 + t];
    float f1 = myH[k * 12 + i1];
    VFMA(a0, f0, h0); VFMA(b0, f0, h1); VFMA(c0, f0, h2);
    VFMA(a1, f1, h0); VFMA(b1, f1, h1); VFMA(c1, f1, h2);
  }
}

// ---- one permuted Fm slot (all 3 rows at once, shared H[c] load) ----------
// Fm symmetric: Fm[r][c] = delta - <H[c,:], W[:,r]>, W[:,r] = Ginv * H[r,:].
template<int g, int k>
__device__ __forceinline__ void slot3(const float* myH, int t,
    const float4* W0, const float4* W1, const float4* W2,
    f2* P0, f2* P1, f2* P2) {
  const int c = 3 * (t ^ GMAP[g]) + k;
  const float4* hc = (const float4*)(myH + c * 12);
  float4 h0 = hc[0], h1 = hc[1], h2 = hc[2];
  float d0 = 0.f, d1 = 0.f, d2 = 0.f;
  FMA4(d0, h0, W0[0]); FMA4(d0, h1, W0[1]); FMA4(d0, h2, W0[2]);
  FMA4(d1, h0, W1[0]); FMA4(d1, h1, W1[1]); FMA4(d1, h2, W1[2]);
  FMA4(d2, h0, W2[0]); FMA4(d2, h1, W2[1]); FMA4(d2, h2, W2[2]);
  constexpr int S = 3 * g + k;
  putS2<S>(P0, ((g == 0 && k == 0) ? 1.0f : 0.0f) - d0);
  putS2<S>(P1, ((g == 0 && k == 1) ? 1.0f : 0.0f) - d1);
  putS2<S>(P2, ((g == 0 && k == 2) ? 1.0f : 0.0f) - d2);
}

// b element in gather-permuted slot S
template<int S>
__device__ __forceinline__ float bgat(const float* bB, int t) {
  constexpr int g = S / 3, k = S % 3;
  return bB[3 * (t ^ GMAP[g]) + k];
}

__global__ __attribute__((amdgpu_flat_work_group_size(BLOCK, BLOCK),
                          amdgpu_waves_per_eu(1, 4)))
void pdhg_kernel(const float* __restrict__ P, const float* __restrict__ q,
                 const float* __restrict__ H, const float* __restrict__ b,
                 const float* __restrict__ cf, const int* __restrict__ itp,
                 float* __restrict__ out, int Btot) {
  __shared__ __align__(16) float sH[EPB * HS];
  __shared__ __align__(16) float sGi[EPB * GS];
  __shared__ __align__(16) float sB[EPB * SS];
  __shared__ __align__(16) float sAux[EPB * SS];

  const int tid  = threadIdx.x;
  const int wq   = tid >> 6;          // wave 0..3 — fully independent
  const int lane = tid & 63;
  const int e    = wq * 8 + (lane >> 3);
  const int t    = lane & 7;
  const int env  = blockIdx.x * EPB + e;
  const int envW0 = blockIdx.x * EPB + wq * 8;
  const int niter = itp[0];
  const int r0w = 3 * t;
  const int i1 = (t < 4) ? t + 8 : t;   // second owned row (safe alias for t>=4)

  // ---- PER-WAVE float4 staging of this wave's 8 envs: H, P, q, b ----
  {
    const float4* gH = (const float4*)(H + (size_t)envW0 * 288);
#pragma unroll
    for (int rep = 0; rep < 9; ++rep) {
      int i = lane + rep * 64;
      int ee = i / 72, off = i - ee * 72;
      *(float4*)&sH[(wq * 8 + ee) * HS + off * 4] = gH[i];
    }
    const float4* gP = (const float4*)(P + (size_t)envW0 * 144);
#pragma unroll
    for (int rep = 0; rep < 4; ++rep) {
      int i = lane + rep * 64;
      int ee = i / 36, off = i - ee * 36;
      *(float4*)&sGi[(wq * 8 + ee) * GS + off * 4] = gP[i];
    }
    { int i = lane + 256; if (lane < 32) {
        int ee = i / 36, off = i - ee * 36;
        *(float4*)&sGi[(wq * 8 + ee) * GS + off * 4] = gP[i]; } }
    const float4* gq = (const float4*)(q + (size_t)envW0 * 12);
    if (lane < 24) {
      int ee = lane / 3, off = lane - ee * 3;
      *(float4*)&sAux[(wq * 8 + ee) * SS + off * 4] = gq[lane];
    }
    const float4* gb = (const float4*)(b + (size_t)envW0 * 24);
    if (lane < 48) {
      int ee = lane / 6, off = lane - ee * 6;
      *(float4*)&sB[(wq * 8 + ee) * SS + off * 4] = gb[lane];
    }
  }
  WFENCE();

  const float* myH = &sH[e * HS];
  float* giB  = &sGi[e * GS];
  float* auxB = &sAux[e * SS];
  float* bBm  = &sB[e * SS];
  const float* bB = bBm;

  // ---- G = P + HtH in registers (rows t, i1); invert in place -------------
  float4 g0a, g0b, g0c, g1a, g1b, g1c;
  gram_rows(myH, t, i1, g0a, g0b, g0c, g1a, g1b, g1c);
  {
    const float4* p0 = (const float4*)(giB + t * 12);
    const float4* p1 = (const float4*)(giB + i1 * 12);
    float4 q0 = p0[0], q1 = p0[1], q2 = p0[2];
    float4 r0 = p1[0], r1 = p1[1], r2 = p1[2];
    ADD4(g0a, q0); ADD4(g0b, q1); ADD4(g0c, q2);
    ADD4(g1a, r0); ADD4(g1b, r1); ADD4(g1c, r2);
  }
  // pivot buffer: aux[12..23] (free until y is written)
  rgj_all<0>(g0a, g0b, g0c, g1a, g1b, g1c, auxB + 12, t);

  // ---- publish Ginv to LDS (overwrites staged P) + y = Ginv*q -------------
  {
    float4* w0 = (float4*)(giB + t * 12);
    w0[0] = g0a; w0[1] = g0b; w0[2] = g0c;
    if (t < 4) {
      float4* w1 = (float4*)(giB + (t + 8) * 12);
      w1[0] = g1a; w1[1] = g1b; w1[2] = g1c;
    }
  }
  float y0 = dot12(g0a, g0b, g0c, auxB);
  float y1 = dot12(g1a, g1b, g1c, auxB);
  WFENCE();
  auxB[12 + t] = y0;
  if (t < 4) auxB[20 + t] = y1;
  WFENCE();

  // ---- own H rows to regs; u = H*y (own rows) -----------------------------
  float4 hr0[3], hr1[3], hr2[3];
  { const float4* p = (const float4*)(myH + (r0w + 0) * 12); hr0[0]=p[0]; hr0[1]=p[1]; hr0[2]=p[2]; }
  { const float4* p = (const float4*)(myH + (r0w + 1) * 12); hr1[0]=p[0]; hr1[1]=p[1]; hr1[2]=p[2]; }
  { const float4* p = (const float4*)(myH + (r0w + 2) * 12); hr2[0]=p[0]; hr2[1]=p[1]; hr2[2]=p[2]; }
  float u0, u1, u2;
  {
    const float4* y4 = (const float4*)(auxB + 12);
    float4 ya = y4[0], yb = y4[1], yc = y4[2];
    u0 = 0.f; FMA4(u0, hr0[0], ya); FMA4(u0, hr0[1], yb); FMA4(u0, hr0[2], yc);
    u1 = 0.f; FMA4(u1, hr1[0], ya); FMA4(u1, hr1[1], yb); FMA4(u1, hr1[2], yc);
    u2 = 0.f; FMA4(u2, hr2[0], ya); FMA4(u2, hr2[1], yb); FMA4(u2, hr2[2], yc);
  }

  // ---- W[:,r] = Ginv * H[r,:] for the 3 own rows (Ginv rows read ONCE) ----
  float4 W0[3], W1[3], W2[3];
  W0[0] = make_float4(0.f,0.f,0.f,0.f); W0[1] = W0[0]; W0[2] = W0[0];
  W1[0] = W0[0]; W1[1] = W0[0]; W1[2] = W0[0];
  W2[0] = W0[0]; W2[1] = W0[0]; W2[2] = W0[0];
#define ACC_W(c, EX)                                                   \
  { const float4* g4 = (const float4*)(giB + (c) * 12);                \
    float4 r0 = g4[0], r1 = g4[1], r2 = g4[2];                         \
    float k0 = hr0[(c) >> 2].EX, k1 = hr1[(c) >> 2].EX, k2 = hr2[(c) >> 2].EX; \
    VFMA(W0[0], k0, r0); VFMA(W0[1], k0, r1); VFMA(W0[2], k0, r2);     \
    VFMA(W1[0], k1, r0); VFMA(W1[1], k1, r1); VFMA(W1[2], k1, r2);     \
    VFMA(W2[0], k2, r0); VFMA(W2[1], k2, r1); VFMA(W2[2], k2, r2); }
  ACC_W(0, x) ACC_W(1, y) ACC_W(2,  z) ACC_W(3,  w)
  ACC_W(4, x) ACC_W(5, y) ACC_W(6,  z) ACC_W(7,  w)
  ACC_W(8, x) ACC_W(9, y) ACC_W(10, z) ACC_W(11, w)
#undef ACC_W

  // ---- column-PERMUTED Fm rows (f2-packed), one pass sharing H[c] loads ---
  f2 pm0[12], pm1[12], pm2[12];
#define SL(g, k) slot3<g, k>(myH, t, W0, W1, W2, pm0, pm1, pm2);
  SL(0,0) SL(0,1) SL(0,2)  SL(1,0) SL(1,1) SL(1,2)
  SL(2,0) SL(2,1) SL(2,2)  SL(3,0) SL(3,1) SL(3,2)
  SL(4,0) SL(4,1) SL(4,2)  SL(5,0) SL(5,1) SL(5,2)
  SL(6,0) SL(6,1) SL(6,2)  SL(7,0) SL(7,1) SL(7,2)
#undef SL

  // ---- mu = H*y - Fm*b (b gathered permuted; bit-exact FMA4 order) --------
  float mu0, mu1, mu2;
  {
    float4 bg0 = make_float4(bgat<0>(bB,t),  bgat<1>(bB,t),  bgat<2>(bB,t),  bgat<3>(bB,t));
    float4 bg1 = make_float4(bgat<4>(bB,t),  bgat<5>(bB,t),  bgat<6>(bB,t),  bgat<7>(bB,t));
    float4 bg2 = make_float4(bgat<8>(bB,t),  bgat<9>(bB,t),  bgat<10>(bB,t), bgat<11>(bB,t));
    float4 bg3 = make_float4(bgat<12>(bB,t), bgat<13>(bB,t), bgat<14>(bB,t), bgat<15>(bB,t));
    float4 bg4 = make_float4(bgat<16>(bB,t), bgat<17>(bB,t), bgat<18>(bB,t), bgat<19>(bB,t));
    float4 bg5 = make_float4(bgat<20>(bB,t), bgat<21>(bB,t), bgat<22>(bB,t), bgat<23>(bB,t));
    float d0 = 0.f, d1 = 0.f, d2 = 0.f;
    FMA4(d0, PMQ(pm0,0), bg0); FMA4(d1, PMQ(pm1,0), bg0); FMA4(d2, PMQ(pm2,0), bg0);
    FMA4(d0, PMQ(pm0,1), bg1); FMA4(d1, PMQ(pm1,1), bg1); FMA4(d2, PMQ(pm2,1), bg1);
    FMA4(d0, PMQ(pm0,2), bg2); FMA4(d1, PMQ(pm1,2), bg2); FMA4(d2, PMQ(pm2,2), bg2);
    FMA4(d0, PMQ(pm0,3), bg3); FMA4(d1, PMQ(pm1,3), bg3); FMA4(d2, PMQ(pm2,3), bg3);
    FMA4(d0, PMQ(pm0,4), bg4); FMA4(d1, PMQ(pm1,4), bg4); FMA4(d2, PMQ(pm2,4), bg4);
    FMA4(d0, PMQ(pm0,5), bg5); FMA4(d1, PMQ(pm1,5), bg5); FMA4(d2, PMQ(pm2,5), bg5);
    mu0 = u0 - d0;
    mu1 = u1 - d1;
    mu2 = u2 - d2;
  }
  float cfr0 = cf[(size_t)env * 24 + r0w];
  float cfr1 = cf[(size_t)env * 24 + r0w + 1];
  float cfr2 = cf[(size_t)env * 24 + r0w + 2];

  // ---- iterations: 21-op DPP all-gather + 36 pk_fma, branchless proj ------
  // Source is availability-ordered: DPP layer L1 -> fill FMAs -> L2 -> fill
  // -> L3, so the scheduler can hide DPP hazards with independent pk_fma.
  const float plo  = (t < 4) ? -3.0e38f : -10.0f;
  const float phi  = (t < 4) ?  3.0e38f :  10.0f;
  const float pthr = (t < 4) ? 0.0f     : -3.0e38f;
  float l0 = 0.f, l1 = 0.f, l2 = 0.f, z0 = 0.f, z1 = 0.f, z2 = 0.f;
#pragma unroll 2
  for (int it = 0; it < niter; ++it) {
    float s0 = l0 + z0, s1 = l1 + z1, s2 = l2 + z2;
    // ---- DPP layer 1 (sources: s) ----
    float g3  = dppv<DPP_XOR1>(s0), g4  = dppv<DPP_XOR1>(s1), g5  = dppv<DPP_XOR1>(s2);
    float g6  = dppv<DPP_XOR2>(s0), g7  = dppv<DPP_XOR2>(s1), g8  = dppv<DPP_XOR2>(s2);
    float g12 = dppv<DPP_HMIR>(s0), g13 = dppv<DPP_HMIR>(s1), g14 = dppv<DPP_HMIR>(s2);
    // fill: pair 0 (s0,s1) on all rows
    f2 vp0 = {s0, s1};
    f2 A0 = {mu0, 0.f}, A1 = {mu1, 0.f}, A2 = {mu2, 0.f};
    A0 = pkfma(pm0[0], vp0, A0); A1 = pkfma(pm1[0], vp0, A1); A2 = pkfma(pm2[0], vp0, A2);
    // ---- DPP layer 2 (sources: layer 1) ----
    float g9  = dppv<DPP_XOR2>(g3),  g10 = dppv<DPP_XOR2>(g4),  g11 = dppv<DPP_XOR2>(g5);
    float g15 = dppv<DPP_HMIR>(g3),  g16 = dppv<DPP_HMIR>(g4),  g17 = dppv<DPP_HMIR>(g5);
    float g18 = dppv<DPP_HMIR>(g6),  g19 = dppv<DPP_HMIR>(g7),  g20 = dppv<DPP_HMIR>(g8);
    // fill: pairs 1-3 (L1 values)
    f2 vp1 = {s2, g3}, vp2 = {g4, g5}, vp3 = {g6, g7};
    A0 = pkfma(pm0[1], vp1, A0); A1 = pkfma(pm1[1], vp1, A1); A2 = pkfma(pm2[1], vp1, A2);
    A0 = pkfma(pm0[2], vp2, A0); A1 = pkfma(pm1[2], vp2, A1); A2 = pkfma(pm2[2], vp2, A2);
    A0 = pkfma(pm0[3], vp3, A0); A1 = pkfma(pm1[3], vp3, A1); A2 = pkfma(pm2[3], vp3, A2);
    // ---- DPP layer 3 ----
    float g21 = dppv<DPP_HMIR>(g9), g22 = dppv<DPP_HMIR>(g10), g23 = dppv<DPP_HMIR>(g11);
    // fill: pairs 4-5 finish A; pairs 6-9 on B
    f2 vp4 = {g8, g9}, vp5 = {g10, g11};
    A0 = pkfma(pm0[4], vp4, A0); A1 = pkfma(pm1[4], vp4, A1); A2 = pkfma(pm2[4], vp4, A2);
    A0 = pkfma(pm0[5], vp5, A0); A1 = pkfma(pm1[5], vp5, A1); A2 = pkfma(pm2[5], vp5, A2);
    f2 vp6 = {g12, g13}, vp7 = {g14, g15}, vp8 = {g16, g17}, vp9 = {g18, g19};
    f2 B0 = {0.f, 0.f}, B1 = {0.f, 0.f}, B2 = {0.f, 0.f};
    B0 = pkfma(pm0[6], vp6, B0); B1 = pkfma(pm1[6], vp6, B1); B2 = pkfma(pm2[6], vp6, B2);
    B0 = pkfma(pm0[7], vp7, B0); B1 = pkfma(pm1[7], vp7, B1); B2 = pkfma(pm2[7], vp7, B2);
    B0 = pkfma(pm0[8], vp8, B0); B1 = pkfma(pm1[8], vp8, B1); B2 = pkfma(pm2[8], vp8, B2);
    B0 = pkfma(pm0[9], vp9, B0); B1 = pkfma(pm1[9], vp9, B1); B2 = pkfma(pm2[9], vp9, B2);
    f2 vp10 = {g20, g21}, vp11 = {g22, g23};
    B0 = pkfma(pm0[10], vp10, B0); B1 = pkfma(pm1[10], vp10, B1); B2 = pkfma(pm2[10], vp10, B2);
    B0 = pkfma(pm0[11], vp11, B0); B1 = pkfma(pm1[11], vp11, B1); B2 = pkfma(pm2[11], vp11, B2);
    // ---- combine + projection ----
    f2 C0 = A0 + B0, C1 = A1 + B1, C2 = A2 + B2;   // v_pk_add_f32
    float w0 = C0.x + C0.y, w1 = C1.x + C1.y, w2 = C2.x + C2.y;
    float zp0 = fmaf(-2.0f, w0, s0);
    float zp1 = fmaf(-2.0f, w1, s1);
    float zp2 = fmaf(-2.0f, w2, s2);
    l0 = w0; l1 = w1; l2 = w2;
    // cone lanes (t<4): no clamp, gate on zp2>0; box lanes: clamp, gate true
    bool gt = zp2 > pthr;
    float e0 = gt ? cfr0 : 0.0f;
    float e1 = gt ? cfr1 : 0.0f;
    float e2 = gt ? cfr2 : 0.0f;
    z0 = __builtin_amdgcn_fmed3f(zp0, plo, phi) * e0;
    z1 = __builtin_amdgcn_fmed3f(zp1, plo, phi) * e1;
    z2 = __builtin_amdgcn_fmed3f(zp2, plo, phi) * e2;
  }

  // ---- outputs: lz, then x = (HtH)^-1 Ht (z - b) --------------------------
  float* xout  = out;
  float* lzout = out + (size_t)Btot * 12;
  lzout[(size_t)env * 48 + r0w]          = l0;
  lzout[(size_t)env * 48 + r0w + 1]      = l1;
  lzout[(size_t)env * 48 + r0w + 2]      = l2;
  lzout[(size_t)env * 48 + 24 + r0w]     = z0;
  lzout[(size_t)env * 48 + 24 + r0w + 1] = z1;
  lzout[(size_t)env * 48 + 24 + r0w + 2] = z2;

  float bo0 = bB[r0w];
  float bo1 = bB[r0w + 1];
  float bo2 = bB[r0w + 2];
  WFENCE();
  auxB[r0w]     = z0 - bo0;
  auxB[r0w + 1] = z1 - bo1;
  auxB[r0w + 2] = z2 - bo2;
  WFENCE();

  // rv = Ht (z - b), both owned columns in one pass, vectorized aux reads
  float rv0 = 0.f, rv8 = 0.f;
  {
    const float4* a4 = (const float4*)auxB;
    float4 au0 = a4[0], au1 = a4[1], au2 = a4[2], au3 = a4[3], au4 = a4[4], au5 = a4[5];
#define RVS(k, AV) { rv0 = fmaf(myH[(k) * 12 + t],  (AV), rv0);   \
                     rv8 = fmaf(myH[(k) * 12 + i1], (AV), rv8); }
    RVS(0,  au0.x) RVS(1,  au0.y) RVS(2,  au0.z) RVS(3,  au0.w)
    RVS(4,  au1.x) RVS(5,  au1.y) RVS(6,  au1.z) RVS(7,  au1.w)
    RVS(8,  au2.x) RVS(9,  au2.y) RVS(10, au2.z) RVS(11, au2.w)
    RVS(12, au3.x) RVS(13, au3.y) RVS(14, au3.z) RVS(15, au3.w)
    RVS(16, au4.x) RVS(17, au4.y) RVS(18, au4.z) RVS(19, au4.w)
    RVS(20, au5.x) RVS(21, au5.y) RVS(22, au5.z) RVS(23, au5.w)
#undef RVS
  }

  // second Gram (no P) + register GJ; pivot buffer reuses sB[0..11]
  gram_rows(myH, t, i1, g0a, g0b, g0c, g1a, g1b, g1c);
  WFENCE();
  auxB[t] = rv0;
  if (t < 4) auxB[t + 8] = rv8;
  WFENCE();
  rgj_all<0>(g0a, g0b, g0c, g1a, g1b, g1c, bBm, t);

  xout[(size_t)env * 12 + t] = dot12(g0a, g0b, g0c, auxB);
  if (t < 4)
    xout[(size_t)env * 12 + t + 8] = dot12(g1a, g1b, g1c, auxB);
}

extern "C" void kernel_launch(void* const* d_in, const int* in_sizes, int n_in,
                              void* d_out, int out_size, void* d_ws, size_t ws_size,
                              hipStream_t stream) {
  const float* P  = (const float*)d_in[0];
  const float* q  = (const float*)d_in[1];
  const float* H  = (const float*)d_in[2];
  const float* b  = (const float*)d_in[3];
  const float* cf = (const float*)d_in[4];
  const int*   it = (const int*)d_in[5];
  float* out = (float*)d_out;
  const int B = in_sizes[1] / 12;       // q is [B,12]
  const int grid = B / EPB;             // 16384/32 = 512 blocks
  pdhg_kernel<<<grid, BLOCK, 0, stream>>>(P, q, H, b, cf, it, out, B);
}